// Round 1
// baseline (2313.275 us; speedup 1.0000x reference)
//
#include <hip/hip_runtime.h>
#include <math.h>

// Problem constants (fixed by reference).
#define HIDDEN 1024
#define MEL    80
#define TSTEPS 1000
#define BATCH  64

// 64 persistent blocks x 1024 threads (16 waves). Block owns 16 hidden units
// = 64 gate rows. Wave wv owns column slice [wv*64, wv*64+64) for ALL 64
// rows; lane = gate row in MAC phase, and lane = column (slot 64*wv+lane)
// in the poll phase. KEY (R7): a wave's MAC needs ONLY the 64 h values its
// own lanes poll -> no block barrier between poll and MAC. Waves run
// decoupled; the single per-step __syncthreads (B) sits before wave0's
// cross-wave reduction.
// R8: mailbox shrunk 8B -> 4B packed {tag:8 | h:Q0.23}. |h|<1 strictly
// (sigmoid*tanh), quant err 2^-24 << 8.3e-4 threshold. Tag lag between any
// producer/consumer is <=2 steps << 256, so 8-bit tags are unambiguous;
// consecutive writes to a slot differ by 2 mod 256. Halves the coherent-path
// poll traffic (8 -> 4 lines per wave sweep) and makes each block's publish
// a single 64B line -> less IC queueing + visibility jitter.
#define NBLK 64
#define TPB  1024

typedef unsigned long long ull;

// v_exp_f32-based activations (abs err ~1e-6 << 8.3e-4 threshold).
__device__ __forceinline__ float sigm_f(float x) { return 1.0f / (1.0f + __expf(-x)); }
__device__ __forceinline__ float tanh_f(float x) { return 1.0f - 2.0f / (1.0f + __expf(2.0f * x)); }

// {tag:8 | q:24}, q = rint(h * 2^23) clamped to +/-(2^23-1).
__device__ __forceinline__ unsigned int pack_h(float h, int tag) {
    int q = (int)rintf(h * 8388608.0f);          // 2^23
    q = max(-8388607, min(8388607, q));
    return ((unsigned int)(tag & 0xFF) << 24) | ((unsigned int)q & 0xFFFFFFu);
}
__device__ __forceinline__ float unpack_h(unsigned int v) {
    int q = ((int)(v << 8)) >> 8;                // sext24
    return (float)q * 1.1920928955078125e-7f;    // * 2^-23
}

__global__ __launch_bounds__(TPB, 4) void tts_recur(
    const float* __restrict__ dec_Wih,   // [4096, 80]
    const float* __restrict__ dec_Whh,   // [4096, 1024]
    const float* __restrict__ dec_bih,   // [4096]
    const float* __restrict__ dec_bhh,   // [4096]
    const float* __restrict__ lin_W,     // [80, 1024]
    const float* __restrict__ lin_b,     // [80]
    float* __restrict__ h_hist,          // [TSTEPS, 1024] (for epilogue)
    unsigned int* __restrict__ hbuf)     // [2, 1024] packed {tag:8|q:24}
{
    const int tid  = threadIdx.x;
    const int blk  = blockIdx.x;
    const int wv   = tid >> 6;           // 0..15: column slice / slot chunk
    const int lane = tid & 63;           // gate row (MAC) / column (poll)
    const int jj   = lane & 15;          // unit within block
    const int gate = lane >> 4;          // i,f,g,o
    const int unit_g = blk * 16 + jj;
    const int row_g  = gate * HIDDEN + unit_g;

    // Producer wave gets issue priority over the 15 spinning consumer waves.
    if (wv == 0) __builtin_amdgcn_s_setprio(3);

    __shared__ __align__(16) float hEx[16][64];   // per-wave h slice (single buffer:
                                                  // wave-private, write-after-read in
                                                  // program order -> no race)
    __shared__ float part[2][64 * 17];            // partials, pitch 17 (2-way = free)

    // ---- one-time fold: w = Whh_row_slice + Wih_row @ lin_W_slice (regs) ----
    const float* wih = dec_Wih + (size_t)row_g * MEL;
    const float* whh = dec_Whh + (size_t)row_g * HIDDEN + wv * 64;
    float4 w[16];
#pragma unroll
    for (int k = 0; k < 16; ++k)
        w[k] = *(const float4*)(whh + k * 4);
#pragma unroll 1
    for (int m = 0; m < MEL; ++m) {
        const float aw = wih[m];
        const float4* lw4 = (const float4*)(lin_W + (size_t)m * HIDDEN + wv * 64);
#pragma unroll
        for (int k = 0; k < 8; ++k) {
            const float4 lw = lw4[k];
            w[k].x = fmaf(aw, lw.x, w[k].x); w[k].y = fmaf(aw, lw.y, w[k].y);
            w[k].z = fmaf(aw, lw.z, w[k].z); w[k].w = fmaf(aw, lw.w, w[k].w);
        }
#pragma unroll
        for (int k = 8; k < 16; ++k) {
            const float4 lw = lw4[k];
            w[k].x = fmaf(aw, lw.x, w[k].x); w[k].y = fmaf(aw, lw.y, w[k].y);
            w[k].z = fmaf(aw, lw.z, w[k].z); w[k].w = fmaf(aw, lw.w, w[k].w);
        }
    }
    float b_comb_r = dec_bih[row_g] + dec_bhh[row_g];
    const float b_dec_r = b_comb_r;                  // step 0 (x=0, no lin_b fold)
    for (int m = 0; m < MEL; ++m)
        b_comb_r = fmaf(wih[m], lin_b[m], b_comb_r);

    float c_prev = 0.0f;                             // live on wave 0 lanes

    // ---- step 0: g = b_dec (h=c=x=0); wave 0 only ----
    if (wv == 0) {
        const float g = b_dec_r;
        const float gi = __shfl(g, jj, 64);
        const float gg = __shfl(g, 32 + jj, 64);
        const float go = __shfl(g, 48 + jj, 64);
        const float c  = sigm_f(gi) * tanh_f(gg);    // f-gate * c0 = 0
        const float h  = sigm_f(go) * tanh_f(c);
        c_prev = c;
        if (lane < 16) {
            __hip_atomic_store(hbuf + unit_g, pack_h(h, 1),
                               __ATOMIC_RELAXED, __HIP_MEMORY_SCOPE_SYSTEM);
            h_hist[unit_g] = h;
        }
    }

    // ---- steps 1..TSTEPS-1 ----
    for (int t = 1; t < TSTEPS; ++t) {
        const int buf = t & 1;
        // Poll own slot (tag==t&0xFF valid). Tag travels with the value in one
        // 4B atomic -> no fences, no cache maintenance. 0xAA poison byte (170)
        // never matches a first poll (wants 1 or 2), and every slot is written
        // each step-pair thereafter. No s_sleep: detection granularity = load
        // latency; sleep only added to it.
        {
            const unsigned int* src = hbuf + ((t - 1) & 1) * HIDDEN;
            const unsigned int want = (unsigned int)t & 0xFFu;
            unsigned int v = __hip_atomic_load(src + tid, __ATOMIC_RELAXED, __HIP_MEMORY_SCOPE_SYSTEM);
            while ((v >> 24) != want)
                v = __hip_atomic_load(src + tid, __ATOMIC_RELAXED, __HIP_MEMORY_SCOPE_SYSTEM);
            hEx[wv][lane] = unpack_h(v);
        }
        // Wave-local exchange: per-wave DS ops execute in program order (HW);
        // wave_barrier stops compiler reordering (rocPRIM warp-exchange idiom).
        __builtin_amdgcn_wave_barrier();

        // Broadcast MAC: 16 uniform-address ds_read_b128 (LDS broadcast, zero
        // conflicts) + 64 fma into 4 accumulators. No block barrier needed.
        const float4* hp = (const float4*)&hEx[wv][0];
        float a0 = 0.f, a1 = 0.f, a2 = 0.f, a3 = 0.f;
#pragma unroll
        for (int k = 0; k < 16; k += 4) {
            const float4 h0 = hp[k], h1 = hp[k + 1], h2 = hp[k + 2], h3 = hp[k + 3];
            a0 = fmaf(w[k].x, h0.x, a0);   a0 = fmaf(w[k].y, h0.y, a0);
            a0 = fmaf(w[k].z, h0.z, a0);   a0 = fmaf(w[k].w, h0.w, a0);
            a1 = fmaf(w[k+1].x, h1.x, a1); a1 = fmaf(w[k+1].y, h1.y, a1);
            a1 = fmaf(w[k+1].z, h1.z, a1); a1 = fmaf(w[k+1].w, h1.w, a1);
            a2 = fmaf(w[k+2].x, h2.x, a2); a2 = fmaf(w[k+2].y, h2.y, a2);
            a2 = fmaf(w[k+2].z, h2.z, a2); a2 = fmaf(w[k+2].w, h2.w, a2);
            a3 = fmaf(w[k+3].x, h3.x, a3); a3 = fmaf(w[k+3].y, h3.y, a3);
            a3 = fmaf(w[k+3].z, h3.z, a3); a3 = fmaf(w[k+3].w, h3.w, a3);
        }
        part[buf][lane * 17 + wv] = (a0 + a1) + (a2 + a3);
        __syncthreads();                               // barrier B (only one/step)

        if (wv == 0) {
            // Reduce 16 partials for this lane's row, then in-wave gates.
            const float* pr = &part[buf][lane * 17];
            float p[16];
#pragma unroll
            for (int i = 0; i < 16; ++i) p[i] = pr[i];
            const float s = (((p[0]+p[1])+(p[2]+p[3])) + ((p[4]+p[5])+(p[6]+p[7])))
                          + (((p[8]+p[9])+(p[10]+p[11])) + ((p[12]+p[13])+(p[14]+p[15])));
            const float g = s + b_comb_r;
            const float gi = __shfl(g, jj, 64);
            const float gf = __shfl(g, 16 + jj, 64);
            const float gg = __shfl(g, 32 + jj, 64);
            const float go = __shfl(g, 48 + jj, 64);
            const float c  = sigm_f(gf) * c_prev + sigm_f(gi) * tanh_f(gg);
            const float h  = sigm_f(go) * tanh_f(c);
            c_prev = c;
            if (lane < 16) {
                __hip_atomic_store(hbuf + buf * HIDDEN + unit_g, pack_h(h, t + 1),
                                   __ATOMIC_RELAXED, __HIP_MEMORY_SCOPE_SYSTEM);
                h_hist[(size_t)t * HIDDEN + unit_g] = h;
            }
        }
        // Race-freedom: part is double-buffered; waves write part[buf^1](t+1)
        // only before barrier B(t+1), which wave0 joins after its part[buf](t)
        // reads. hEx is wave-private with program-order write-after-read.
        // hbuf overwrite (h(t) over h(t-2)): P publishes h(t) only after
        // barrier B(t) <- P observed ALL tags t <- every block Q published
        // h(t-1) <- Q's barrier B(t-1) <- Q fully consumed h(t-2). QED.
        // 8-bit tag safety: slot content lags the poll target by <=2 steps,
        // and consecutive slot writes differ by 2 mod 256 -> no aliasing.
    }
}

// Epilogue: frame[t] = lin_W @ h[t] + lin_b, broadcast to 64 batch rows.
__global__ __launch_bounds__(128) void tts_frames(
    const float* __restrict__ lin_W, const float* __restrict__ lin_b,
    const float* __restrict__ h_hist, float* __restrict__ out)
{
    const int t = blockIdx.x;
    const int tid = threadIdx.x;
    __shared__ __align__(16) float h_sh[HIDDEN];
    __shared__ float f_s[MEL];
    const float4* src = (const float4*)(h_hist + (size_t)t * HIDDEN);
    ((float4*)h_sh)[tid] = src[tid];
    ((float4*)h_sh)[tid + 128] = src[tid + 128];
    __syncthreads();
    if (tid < MEL) {
        const float* wrow = lin_W + (size_t)tid * HIDDEN;
        float acc = lin_b[tid];
#pragma unroll 8
        for (int c = 0; c < HIDDEN; ++c)
            acc = fmaf(wrow[c], h_sh[c], acc);
        f_s[tid] = acc;
    }
    __syncthreads();
    for (int idx = tid; idx < BATCH * MEL; idx += 128) {
        const int b = idx / MEL;
        const int m = idx - b * MEL;
        out[(size_t)b * TSTEPS * MEL + (size_t)t * MEL + m] = f_s[m];
    }
}

extern "C" void kernel_launch(void* const* d_in, const int* in_sizes, int n_in,
                              void* d_out, int out_size, void* d_ws, size_t ws_size,
                              hipStream_t stream) {
    // Inputs: 0 text, 1 text_lens, 2 max_audio_len, 3 W_emb, 4..7 enc_*,
    // 8..11 dec_{Wih,Whh,bih,bhh}, 12 lin_W, 13 lin_b. Encoder is dead code.
    const float* dec_Wih = (const float*)d_in[8];
    const float* dec_Whh = (const float*)d_in[9];
    const float* dec_bih = (const float*)d_in[10];
    const float* dec_bhh = (const float*)d_in[11];
    const float* lin_W   = (const float*)d_in[12];
    const float* lin_b   = (const float*)d_in[13];
    float* out = (float*)d_out;

    // Workspace: h_hist fp32 [1000][1024] (4,096,000 B) + hbuf [2][1024] uint.
    // 0xAA poison -> tag byte 170 never matches the first polls -> no init pass.
    float* h_hist = (float*)d_ws;
    unsigned int* hbuf = (unsigned int*)((char*)d_ws + (size_t)TSTEPS * HIDDEN * sizeof(float));

    hipLaunchKernelGGL(tts_recur, dim3(NBLK), dim3(TPB), 0, stream,
                       dec_Wih, dec_Whh, dec_bih, dec_bhh, lin_W, lin_b, h_hist, hbuf);
    hipLaunchKernelGGL(tts_frames, dim3(TSTEPS), dim3(128), 0, stream,
                       lin_W, lin_b, h_hist, out);
}

// Round 2
// 2304.163 us; speedup vs baseline: 1.0040x; 1.0040x over previous
//
#include <hip/hip_runtime.h>
#include <math.h>

// Problem constants (fixed by reference).
#define HIDDEN 1024
#define MEL    80
#define TSTEPS 1000
#define BATCH  64

// 64 persistent blocks x 1024 threads (16 waves). Block owns 16 hidden units
// = 64 gate rows. Wave wv owns column slice [wv*64, wv*64+64) for ALL 64
// rows; lane = gate row in MAC phase, and lane = column (slot 64*wv+lane)
// in the poll phase. KEY (R7): a wave's MAC needs ONLY the 64 h values its
// own lanes poll -> no block barrier between poll and MAC. Waves run
// decoupled; the single per-step __syncthreads (B) sits before wave0's
// cross-wave reduction.
// R8: mailbox packed 4B {tag:8 | h:Q0.23}. Quant err 2^-24 << 8.3e-4.
// R9: mailbox atomomics SYSTEM -> AGENT scope. System scope forced the
// fine-grained path to be host-coherent (polls observed reaching HBM in
// FETCH_SIZE: ~14 MB on a 4 KB buffer); agent scope is sufficient for
// cross-XCD visibility (device coherence point = IC) and cuts the poll
// round trip from HBM latency (~900 cy) to IC latency.
#define NBLK 64
#define TPB  1024

typedef unsigned long long ull;

// v_exp_f32-based activations (abs err ~1e-6 << 8.3e-4 threshold).
__device__ __forceinline__ float sigm_f(float x) { return 1.0f / (1.0f + __expf(-x)); }
__device__ __forceinline__ float tanh_f(float x) { return 1.0f - 2.0f / (1.0f + __expf(2.0f * x)); }

// {tag:8 | q:24}, q = rint(h * 2^23) clamped to +/-(2^23-1).
__device__ __forceinline__ unsigned int pack_h(float h, int tag) {
    int q = (int)rintf(h * 8388608.0f);          // 2^23
    q = max(-8388607, min(8388607, q));
    return ((unsigned int)(tag & 0xFF) << 24) | ((unsigned int)q & 0xFFFFFFu);
}
__device__ __forceinline__ float unpack_h(unsigned int v) {
    int q = ((int)(v << 8)) >> 8;                // sext24
    return (float)q * 1.1920928955078125e-7f;    // * 2^-23
}

__global__ __launch_bounds__(TPB, 4) void tts_recur(
    const float* __restrict__ dec_Wih,   // [4096, 80]
    const float* __restrict__ dec_Whh,   // [4096, 1024]
    const float* __restrict__ dec_bih,   // [4096]
    const float* __restrict__ dec_bhh,   // [4096]
    const float* __restrict__ lin_W,     // [80, 1024]
    const float* __restrict__ lin_b,     // [80]
    float* __restrict__ h_hist,          // [TSTEPS, 1024] (for epilogue)
    unsigned int* __restrict__ hbuf)     // [2, 1024] packed {tag:8|q:24}
{
    const int tid  = threadIdx.x;
    const int blk  = blockIdx.x;
    const int wv   = tid >> 6;           // 0..15: column slice / slot chunk
    const int lane = tid & 63;           // gate row (MAC) / column (poll)
    const int jj   = lane & 15;          // unit within block
    const int gate = lane >> 4;          // i,f,g,o
    const int unit_g = blk * 16 + jj;
    const int row_g  = gate * HIDDEN + unit_g;

    // Producer wave gets issue priority over the 15 spinning consumer waves.
    if (wv == 0) __builtin_amdgcn_s_setprio(3);

    __shared__ __align__(16) float hEx[16][64];   // per-wave h slice (single buffer:
                                                  // wave-private, write-after-read in
                                                  // program order -> no race)
    __shared__ float part[2][64 * 17];            // partials, pitch 17 (2-way = free)

    // ---- one-time fold: w = Whh_row_slice + Wih_row @ lin_W_slice (regs) ----
    const float* wih = dec_Wih + (size_t)row_g * MEL;
    const float* whh = dec_Whh + (size_t)row_g * HIDDEN + wv * 64;
    float4 w[16];
#pragma unroll
    for (int k = 0; k < 16; ++k)
        w[k] = *(const float4*)(whh + k * 4);
#pragma unroll 1
    for (int m = 0; m < MEL; ++m) {
        const float aw = wih[m];
        const float4* lw4 = (const float4*)(lin_W + (size_t)m * HIDDEN + wv * 64);
#pragma unroll
        for (int k = 0; k < 8; ++k) {
            const float4 lw = lw4[k];
            w[k].x = fmaf(aw, lw.x, w[k].x); w[k].y = fmaf(aw, lw.y, w[k].y);
            w[k].z = fmaf(aw, lw.z, w[k].z); w[k].w = fmaf(aw, lw.w, w[k].w);
        }
#pragma unroll
        for (int k = 8; k < 16; ++k) {
            const float4 lw = lw4[k];
            w[k].x = fmaf(aw, lw.x, w[k].x); w[k].y = fmaf(aw, lw.y, w[k].y);
            w[k].z = fmaf(aw, lw.z, w[k].z); w[k].w = fmaf(aw, lw.w, w[k].w);
        }
    }
    float b_comb_r = dec_bih[row_g] + dec_bhh[row_g];
    const float b_dec_r = b_comb_r;                  // step 0 (x=0, no lin_b fold)
    for (int m = 0; m < MEL; ++m)
        b_comb_r = fmaf(wih[m], lin_b[m], b_comb_r);

    float c_prev = 0.0f;                             // live on wave 0 lanes

    // ---- step 0: g = b_dec (h=c=x=0); wave 0 only ----
    if (wv == 0) {
        const float g = b_dec_r;
        const float gi = __shfl(g, jj, 64);
        const float gg = __shfl(g, 32 + jj, 64);
        const float go = __shfl(g, 48 + jj, 64);
        const float c  = sigm_f(gi) * tanh_f(gg);    // f-gate * c0 = 0
        const float h  = sigm_f(go) * tanh_f(c);
        c_prev = c;
        if (lane < 16) {
            __hip_atomic_store(hbuf + unit_g, pack_h(h, 1),
                               __ATOMIC_RELAXED, __HIP_MEMORY_SCOPE_AGENT);
            h_hist[unit_g] = h;
        }
    }

    // ---- steps 1..TSTEPS-1 ----
    for (int t = 1; t < TSTEPS; ++t) {
        const int buf = t & 1;
        // Poll own slot (tag==t&0xFF valid). Tag travels with the value in one
        // 4B atomic -> no fences, no cache maintenance. 0xAA poison byte (170)
        // never matches a first poll (wants 1 or 2), and every slot is written
        // each step-pair thereafter. No s_sleep: detection granularity = load
        // latency; sleep only added to it.
        {
            const unsigned int* src = hbuf + ((t - 1) & 1) * HIDDEN;
            const unsigned int want = (unsigned int)t & 0xFFu;
            unsigned int v = __hip_atomic_load(src + tid, __ATOMIC_RELAXED, __HIP_MEMORY_SCOPE_AGENT);
            while ((v >> 24) != want)
                v = __hip_atomic_load(src + tid, __ATOMIC_RELAXED, __HIP_MEMORY_SCOPE_AGENT);
            hEx[wv][lane] = unpack_h(v);
        }
        // Wave-local exchange: per-wave DS ops execute in program order (HW);
        // wave_barrier stops compiler reordering (rocPRIM warp-exchange idiom).
        __builtin_amdgcn_wave_barrier();

        // Broadcast MAC: 16 uniform-address ds_read_b128 (LDS broadcast, zero
        // conflicts) + 64 fma into 4 accumulators. No block barrier needed.
        const float4* hp = (const float4*)&hEx[wv][0];
        float a0 = 0.f, a1 = 0.f, a2 = 0.f, a3 = 0.f;
#pragma unroll
        for (int k = 0; k < 16; k += 4) {
            const float4 h0 = hp[k], h1 = hp[k + 1], h2 = hp[k + 2], h3 = hp[k + 3];
            a0 = fmaf(w[k].x, h0.x, a0);   a0 = fmaf(w[k].y, h0.y, a0);
            a0 = fmaf(w[k].z, h0.z, a0);   a0 = fmaf(w[k].w, h0.w, a0);
            a1 = fmaf(w[k+1].x, h1.x, a1); a1 = fmaf(w[k+1].y, h1.y, a1);
            a1 = fmaf(w[k+1].z, h1.z, a1); a1 = fmaf(w[k+1].w, h1.w, a1);
            a2 = fmaf(w[k+2].x, h2.x, a2); a2 = fmaf(w[k+2].y, h2.y, a2);
            a2 = fmaf(w[k+2].z, h2.z, a2); a2 = fmaf(w[k+2].w, h2.w, a2);
            a3 = fmaf(w[k+3].x, h3.x, a3); a3 = fmaf(w[k+3].y, h3.y, a3);
            a3 = fmaf(w[k+3].w, h3.w, a3); a3 = fmaf(w[k+3].z, h3.z, a3);
        }
        part[buf][lane * 17 + wv] = (a0 + a1) + (a2 + a3);
        __syncthreads();                               // barrier B (only one/step)

        if (wv == 0) {
            // Reduce 16 partials for this lane's row, then in-wave gates.
            const float* pr = &part[buf][lane * 17];
            float p[16];
#pragma unroll
            for (int i = 0; i < 16; ++i) p[i] = pr[i];
            const float s = (((p[0]+p[1])+(p[2]+p[3])) + ((p[4]+p[5])+(p[6]+p[7])))
                          + (((p[8]+p[9])+(p[10]+p[11])) + ((p[12]+p[13])+(p[14]+p[15])));
            const float g = s + b_comb_r;
            const float gi = __shfl(g, jj, 64);
            const float gf = __shfl(g, 16 + jj, 64);
            const float gg = __shfl(g, 32 + jj, 64);
            const float go = __shfl(g, 48 + jj, 64);
            const float c  = sigm_f(gf) * c_prev + sigm_f(gi) * tanh_f(gg);
            const float h  = sigm_f(go) * tanh_f(c);
            c_prev = c;
            if (lane < 16) {
                __hip_atomic_store(hbuf + buf * HIDDEN + unit_g, pack_h(h, t + 1),
                                   __ATOMIC_RELAXED, __HIP_MEMORY_SCOPE_AGENT);
                h_hist[(size_t)t * HIDDEN + unit_g] = h;
            }
        }
        // Race-freedom: part is double-buffered; waves write part[buf^1](t+1)
        // only before barrier B(t+1), which wave0 joins after its part[buf](t)
        // reads. hEx is wave-private with program-order write-after-read.
        // hbuf overwrite (h(t) over h(t-2)): P publishes h(t) only after
        // barrier B(t) <- P observed ALL tags t <- every block Q published
        // h(t-1) <- Q's barrier B(t-1) <- Q fully consumed h(t-2). QED.
        // 8-bit tag safety: slot content lags the poll target by <=2 steps,
        // and consecutive slot writes differ by 2 mod 256 -> no aliasing.
    }
}

// Epilogue: frame[t] = lin_W @ h[t] + lin_b, broadcast to 64 batch rows.
__global__ __launch_bounds__(128) void tts_frames(
    const float* __restrict__ lin_W, const float* __restrict__ lin_b,
    const float* __restrict__ h_hist, float* __restrict__ out)
{
    const int t = blockIdx.x;
    const int tid = threadIdx.x;
    __shared__ __align__(16) float h_sh[HIDDEN];
    __shared__ float f_s[MEL];
    const float4* src = (const float4*)(h_hist + (size_t)t * HIDDEN);
    ((float4*)h_sh)[tid] = src[tid];
    ((float4*)h_sh)[tid + 128] = src[tid + 128];
    __syncthreads();
    if (tid < MEL) {
        const float* wrow = lin_W + (size_t)tid * HIDDEN;
        float acc = lin_b[tid];
#pragma unroll 8
        for (int c = 0; c < HIDDEN; ++c)
            acc = fmaf(wrow[c], h_sh[c], acc);
        f_s[tid] = acc;
    }
    __syncthreads();
    for (int idx = tid; idx < BATCH * MEL; idx += 128) {
        const int b = idx / MEL;
        const int m = idx - b * MEL;
        out[(size_t)b * TSTEPS * MEL + (size_t)t * MEL + m] = f_s[m];
    }
}

extern "C" void kernel_launch(void* const* d_in, const int* in_sizes, int n_in,
                              void* d_out, int out_size, void* d_ws, size_t ws_size,
                              hipStream_t stream) {
    // Inputs: 0 text, 1 text_lens, 2 max_audio_len, 3 W_emb, 4..7 enc_*,
    // 8..11 dec_{Wih,Whh,bih,bhh}, 12 lin_W, 13 lin_b. Encoder is dead code.
    const float* dec_Wih = (const float*)d_in[8];
    const float* dec_Whh = (const float*)d_in[9];
    const float* dec_bih = (const float*)d_in[10];
    const float* dec_bhh = (const float*)d_in[11];
    const float* lin_W   = (const float*)d_in[12];
    const float* lin_b   = (const float*)d_in[13];
    float* out = (float*)d_out;

    // Workspace: h_hist fp32 [1000][1024] (4,096,000 B) + hbuf [2][1024] uint.
    // 0xAA poison -> tag byte 170 never matches the first polls -> no init pass.
    float* h_hist = (float*)d_ws;
    unsigned int* hbuf = (unsigned int*)((char*)d_ws + (size_t)TSTEPS * HIDDEN * sizeof(float));

    hipLaunchKernelGGL(tts_recur, dim3(NBLK), dim3(TPB), 0, stream,
                       dec_Wih, dec_Whh, dec_bih, dec_bhh, lin_W, lin_b, h_hist, hbuf);
    hipLaunchKernelGGL(tts_frames, dim3(TSTEPS), dim3(128), 0, stream,
                       lin_W, lin_b, h_hist, out);
}